// Round 1
// 1326.299 us; speedup vs baseline: 5.9107x; 5.9107x over previous
//
#include <hip/hip_runtime.h>

#define NN 100000
#define NE 800000
#define NL 200000
#define HEADS 4

// ---------------- small-N row GEMM (kept for ncols==32) ---------------------
// A is [n_rows, K] row-major, B is [K, ncols] row-major.
template<int K, int TPB, int RPB, bool RELU, bool BIAS>
__launch_bounds__(TPB)
__global__ void gemm_rows(const float* __restrict__ A, const float* __restrict__ B,
                          const float* __restrict__ bias, float* __restrict__ C,
                          int n_rows, int ncols) {
    __shared__ float As[RPB][K];
    const int row0 = blockIdx.x * RPB;
    for (int i = threadIdx.x; i < RPB * K; i += TPB) {
        int r = i / K, k = i % K;
        int gr = row0 + r;
        As[r][k] = (gr < n_rows) ? A[(size_t)gr * K + k] : 0.f;
    }
    __syncthreads();
    const int cpr = TPB / RPB;              // threads per row
    const int r   = threadIdx.x / cpr;
    const int j0  = threadIdx.x % cpr;
    const int gr  = row0 + r;
    if (gr >= n_rows) return;
    for (int j = j0; j < ncols; j += cpr) {
        float s = BIAS ? bias[j] : 0.f;
        #pragma unroll
        for (int k = 0; k < K; ++k) s += As[r][k] * B[k * ncols + j];
        if (RELU) s = fmaxf(s, 0.f);
        C[(size_t)gr * ncols + j] = s;
    }
}

// ---------------- tiled register-blocked GEMM -------------------------------
// C[M,N] = act(A[M,K] @ B[K,N] + bias); row-major; requires K%32==0, N%4==0.
// Block: 64 rows x BN cols, 256 threads. Thread (ty=tid/16, tx=tid%16) owns a
// 4x4 (BN=64) or 4x(4+4) (BN=128, halves 64 apart) register tile.
// A staged TRANSPOSED in LDS with XOR swizzle so both the transpose-writes and
// the per-k b128 fragment reads are bank-conflict-free.
template<int K, int BN, bool RELU, bool BIAS>
__launch_bounds__(256, 4)
__global__ void gemm_tiled(const float* __restrict__ A, const float* __restrict__ B,
                           const float* __restrict__ bias, float* __restrict__ C,
                           int M, int N) {
    constexpr int BM = 64, BK = 32;
    constexpr int TN = BN / 16;
    // As[kk][r ^ (((kk>>2)&3)<<3)] holds A[row0+r][k0+kk]
    __shared__ float As[BK][BM];
    __shared__ float Bs[BK][BN];

    const int tid  = threadIdx.x;
    const int row0 = blockIdx.x * BM;
    const int col0 = blockIdx.y * BN;
    const int ty   = tid >> 4;
    const int tx   = tid & 15;

    float acc[4][TN];
    #pragma unroll
    for (int i = 0; i < 4; ++i)
        #pragma unroll
        for (int j = 0; j < TN; ++j) acc[i][j] = 0.f;

    for (int k0 = 0; k0 < K; k0 += BK) {
        // --- stage A chunk: coalesced float4 loads, swizzled transposed stores
        for (int i = tid * 4; i < BM * BK; i += 1024) {
            int r  = i >> 5;          // i / BK
            int kk = i & 31;          // i % BK, multiple of 4
            int gr = row0 + r;
            float4 v = make_float4(0.f, 0.f, 0.f, 0.f);
            if (gr < M) v = *(const float4*)(A + (size_t)gr * K + k0 + kk);
            int sw = ((kk >> 2) & 3) << 3;   // same for kk..kk+3
            As[kk + 0][r ^ sw] = v.x;
            As[kk + 1][r ^ sw] = v.y;
            As[kk + 2][r ^ sw] = v.z;
            As[kk + 3][r ^ sw] = v.w;
        }
        // --- stage B chunk: coalesced float4
        for (int i = tid * 4; i < BK * BN; i += 1024) {
            int kk = i / BN, c = i % BN;
            int gc = col0 + c;
            float4 v = make_float4(0.f, 0.f, 0.f, 0.f);
            if (gc < N) v = *(const float4*)(B + (size_t)(k0 + kk) * N + gc);
            *(float4*)&Bs[kk][c] = v;
        }
        __syncthreads();

        #pragma unroll
        for (int kk = 0; kk < BK; ++kk) {
            int sw = ((kk >> 2) & 3) << 3;
            float4 a  = *(const float4*)&As[kk][(ty * 4) ^ sw];
            float4 b0 = *(const float4*)&Bs[kk][tx * 4];
            float av[4] = {a.x, a.y, a.z, a.w};
            float bv[TN];
            bv[0] = b0.x; bv[1] = b0.y; bv[2] = b0.z; bv[3] = b0.w;
            if constexpr (TN == 8) {
                float4 b1 = *(const float4*)&Bs[kk][64 + tx * 4];
                bv[4] = b1.x; bv[5] = b1.y; bv[6] = b1.z; bv[7] = b1.w;
            }
            #pragma unroll
            for (int i = 0; i < 4; ++i)
                #pragma unroll
                for (int j = 0; j < TN; ++j)
                    acc[i][j] = fmaf(av[i], bv[j], acc[i][j]);
        }
        __syncthreads();
    }

    #pragma unroll
    for (int i = 0; i < 4; ++i) {
        int gr = row0 + ty * 4 + i;
        if (gr >= M) continue;
        #pragma unroll
        for (int jh = 0; jh < TN / 4; ++jh) {
            int gc = col0 + jh * 64 + tx * 4;
            if (gc >= N) continue;
            float4 o = make_float4(acc[i][jh * 4 + 0], acc[i][jh * 4 + 1],
                                   acc[i][jh * 4 + 2], acc[i][jh * 4 + 3]);
            if (BIAS) { o.x += bias[gc]; o.y += bias[gc + 1]; o.z += bias[gc + 2]; o.w += bias[gc + 3]; }
            if (RELU) { o.x = fmaxf(o.x, 0.f); o.y = fmaxf(o.y, 0.f); o.z = fmaxf(o.z, 0.f); o.w = fmaxf(o.w, 0.f); }
            *(float4*)(C + (size_t)gr * N + gc) = o;
        }
    }
}

// ---------------- per-(node,head) attention logits --------------------------
template<int C>
__global__ void calc_alpha(const float* __restrict__ h, const float* __restrict__ a_src,
                           const float* __restrict__ a_dst, float* __restrict__ as_out,
                           float* __restrict__ ad_out) {
    int i = blockIdx.x * blockDim.x + threadIdx.x;   // n*HEADS + hd
    if (i >= NN * HEADS) return;
    int n = i / HEADS, hd = i % HEADS;
    const float* hp  = h + (size_t)n * HEADS * C + hd * C;
    const float* asp = a_src + hd * C;
    const float* adp = a_dst + hd * C;
    float s1 = 0.f, s2 = 0.f;
    #pragma unroll 8
    for (int c = 0; c < C; ++c) { float v = hp[c]; s1 += v * asp[c]; s2 += v * adp[c]; }
    as_out[i] = s1; ad_out[i] = s2;
}

__device__ __forceinline__ float lrelu02(float v) { return v > 0.f ? v : 0.2f * v; }

// ---------------- softmax denominator per (dst, head) -----------------------
__global__ void edge_denom(const int* __restrict__ src, const int* __restrict__ dst,
                           const float* __restrict__ as_, const float* __restrict__ ad_,
                           float* __restrict__ den) {
    int i = blockIdx.x * blockDim.x + threadIdx.x;   // e*HEADS + hd
    if (i >= NE * HEADS) return;
    int e = i / HEADS, hd = i % HEADS;
    int s = src[e], d = dst[e];
    float v = lrelu02(as_[s * HEADS + hd] + ad_[d * HEADS + hd]);
    atomicAdd(&den[d * HEADS + hd], __expf(v));
}

// ---------------- weighted aggregation, heads folded ------------------------
template<int C>
__global__ void edge_agg(const int* __restrict__ src, const int* __restrict__ dst,
                         const float* __restrict__ as_, const float* __restrict__ ad_,
                         const float* __restrict__ den, const float* __restrict__ h,
                         float* __restrict__ agg) {
    int tid = blockIdx.x * blockDim.x + threadIdx.x;
    int e = tid / C, c = tid % C;
    if (e >= NE) return;
    int s = src[e], d = dst[e];
    float w[HEADS];
    #pragma unroll
    for (int hd = 0; hd < HEADS; ++hd) {
        float v = lrelu02(as_[s * HEADS + hd] + ad_[d * HEADS + hd]);
        w[hd] = __expf(v) / (den[d * HEADS + hd] + 1e-16f);
    }
    float sum = 0.f;
    #pragma unroll
    for (int hd = 0; hd < HEADS; ++hd)
        sum += w[hd] * h[(size_t)s * HEADS * C + hd * C + c];
    atomicAdd(&agg[(size_t)d * C + c], sum);
}

// ---------------- mean over heads + bias + relu ------------------------------
template<int C>
__global__ void finalize(const float* __restrict__ agg, const float* __restrict__ bias,
                         float* __restrict__ out) {
    int i = blockIdx.x * blockDim.x + threadIdx.x;   // n*C + c
    if (i >= NN * C) return;
    out[i] = fmaxf(agg[i] * 0.25f + bias[i % C], 0.f);
}

// ---------------- link decoder ----------------------------------------------
__global__ void link_kernel(const int* __restrict__ lsrc, const int* __restrict__ ldst,
                            const float* __restrict__ z, float* __restrict__ out) {
    int e = blockIdx.x * blockDim.x + threadIdx.x;
    if (e >= NL) return;
    const float4* zs = (const float4*)(z + (size_t)lsrc[e] * 32);
    const float4* zd = (const float4*)(z + (size_t)ldst[e] * 32);
    float sum = 0.f;
    #pragma unroll
    for (int i = 0; i < 8; ++i) {
        float4 a = zs[i], b = zd[i];
        sum += a.x * b.x + a.y * b.y + a.z * b.z + a.w * b.w;
    }
    out[e] = sum;
}

extern "C" void kernel_launch(void* const* d_in, const int* in_sizes, int n_in,
                              void* d_out, int out_size, void* d_ws, size_t ws_size,
                              hipStream_t stream) {
    const float* x     = (const float*)d_in[0];
    const int*   ei    = (const int*)d_in[1];
    const int*   eli   = (const int*)d_in[2];
    const float* W0    = (const float*)d_in[3];
    const float* as0   = (const float*)d_in[4];
    const float* ad0   = (const float*)d_in[5];
    const float* b0    = (const float*)d_in[6];
    const float* W1    = (const float*)d_in[7];
    const float* as1   = (const float*)d_in[8];
    const float* ad1   = (const float*)d_in[9];
    const float* b1    = (const float*)d_in[10];
    const float* lin_w = (const float*)d_in[11];
    const float* lin_b = (const float*)d_in[12];
    const float* d1_w  = (const float*)d_in[13];
    const float* d1_b  = (const float*)d_in[14];
    const float* d2_w  = (const float*)d_in[15];
    const float* d2_b  = (const float*)d_in[16];
    const float* d3_w  = (const float*)d_in[17];
    const float* d3_b  = (const float*)d_in[18];
    const float* d4_w  = (const float*)d_in[19];
    const float* d4_b  = (const float*)d_in[20];

    const int* src = ei;            // edge_index[0]
    const int* dst = ei + NE;       // edge_index[1]
    const int* ls  = eli;
    const int* ld  = eli + NL;

    float* ws = (float*)d_ws;
    // layout (floats): h [N*256] | agg [N*64] | out0/out1 [N*64] | as [N*4] | ad [N*4] | den [N*4]
    float* h_buf = ws;
    float* agg   = ws + (size_t)NN * 256;
    float* outb  = ws + (size_t)NN * 320;
    float* asb   = ws + (size_t)NN * 384;
    float* adb   = ws + (size_t)NN * 388;
    float* den   = ws + (size_t)NN * 392;
    // decoder intermediates reuse the h region
    float* z  = h_buf;                       // [N,32]
    float* e1 = h_buf + (size_t)NN * 32;     // [N,32]
    float* e2 = h_buf + (size_t)NN * 64;     // [N,64]
    float* e3 = h_buf + (size_t)NN * 128;    // [N,96]

    float* link_out = (float*)d_out;
    float* expr_out = (float*)d_out + NL;

    const int GM = (NN + 63) / 64;           // 1563 row-tiles

    // ---------------- Layer 0 (C=64 per head) ----------------
    gemm_tiled<64, 128, false, false><<<dim3(GM, 2), 256, 0, stream>>>(x, W0, nullptr, h_buf, NN, 256);
    calc_alpha<64><<<(NN * HEADS + 255) / 256, 256, 0, stream>>>(h_buf, as0, ad0, asb, adb);
    hipMemsetAsync(den, 0, (size_t)NN * HEADS * 4, stream);
    edge_denom<<<(NE * HEADS + 255) / 256, 256, 0, stream>>>(src, dst, asb, adb, den);
    hipMemsetAsync(agg, 0, (size_t)NN * 64 * 4, stream);
    edge_agg<64><<<(size_t)(NE * 64) / 256, 256, 0, stream>>>(src, dst, asb, adb, den, h_buf, agg);
    finalize<64><<<(NN * 64) / 256, 256, 0, stream>>>(agg, b0, outb);

    // ---------------- Layer 1 (C=32 per head) ----------------
    gemm_tiled<64, 128, false, false><<<dim3(GM, 1), 256, 0, stream>>>(outb, W1, nullptr, h_buf, NN, 128);
    calc_alpha<32><<<(NN * HEADS + 255) / 256, 256, 0, stream>>>(h_buf, as1, ad1, asb, adb);
    hipMemsetAsync(den, 0, (size_t)NN * HEADS * 4, stream);
    edge_denom<<<(NE * HEADS + 255) / 256, 256, 0, stream>>>(src, dst, asb, adb, den);
    hipMemsetAsync(agg, 0, (size_t)NN * 32 * 4, stream);
    edge_agg<32><<<(size_t)(NE * 32) / 256, 256, 0, stream>>>(src, dst, asb, adb, den, h_buf, agg);
    finalize<32><<<(NN * 32) / 256, 256, 0, stream>>>(agg, b1, outb);

    // ---------------- lin: z = out1 @ lin_w + lin_b ----------------
    gemm_rows<32, 256, 8, false, true><<<NN / 8, 256, 0, stream>>>(outb, lin_w, lin_b, z, NN, 32);

    // ---------------- link decoder ----------------
    link_kernel<<<(NL + 255) / 256, 256, 0, stream>>>(ls, ld, z, link_out);

    // ---------------- expression decoder ----------------
    gemm_rows<32, 256, 8, true, true><<<NN / 8, 256, 0, stream>>>(z, d1_w, d1_b, e1, NN, 32);
    gemm_tiled<32, 64,  true,  true><<<dim3(GM, 1), 256, 0, stream>>>(e1, d2_w, d2_b, e2, NN, 64);
    gemm_tiled<64, 64,  true,  true><<<dim3(GM, 2), 256, 0, stream>>>(e2, d3_w, d3_b, e3, NN, 96);
    gemm_tiled<96, 128, false, true><<<dim3(GM, 4), 256, 0, stream>>>(e3, d4_w, d4_b, expr_out, NN, 500);
}